// Round 14
// baseline (116.655 us; speedup 1.0000x reference)
//
#include <hip/hip_runtime.h>
#include <hip/hip_bf16.h>

// FlashAttentionVarlen, bf16 32x32x16-MFMA flash attention, fp32 in/out.
// B=128 seqs (L in {128,256}), H=16, D=64, packed T=24576.
// R14 = R13 (113.8 us, verified) + ONE change: QK dependent-chain split.
// R13 ran QK as 2 chains of depth 8 (8 serial MFMAs into sc0/sc1). Now 4
// independent chains of depth 4 (sc0,tc0,sc1,tc1; qh-chain and ql-chain
// per key-half), collapsed with VALU adds that overlap the matrix pipe.
// Rationale: kernel is latency-bound (warm==cold duration, all pipes <30%,
// compute-thinning neutral in R11). R9 tested this theory but was poisoned
// by spills ((256,3) -> 84-reg cap); (512,2) = 128-reg cap fits +32 regs.
// Everything else identical to R13: K bf16-hi LDS (33 KB dbuf), Q hi+lo
// regs, V bf16-hi, P bf16-hi, swapped QK, in-register softmax, shfl_xor(32)
// P redistribute, one barrier per tile, 8-wave (b,h) blocks, stage-once.

using bf16x8 = __attribute__((ext_vector_type(8))) short;
using u16x8  = __attribute__((ext_vector_type(8))) unsigned short;
using u32x4  = __attribute__((ext_vector_type(4))) unsigned;
using f32x16 = __attribute__((ext_vector_type(16))) float;

#define MFMA32(a, b, c) __builtin_amdgcn_mfma_f32_32x32x16_bf16((a), (b), (c), 0, 0, 0)

constexpr int H  = 16;
constexpr int D  = 64;
constexpr int RS = H * D;                              // packed row stride (floats)
constexpr float QSCALE = 0.125f * 1.44269504088896f;   // 1/sqrt(64) * log2(e)
constexpr float THR    = 11.5f;                        // defer-max threshold (log2)

__device__ inline unsigned short bfbits(float x) {
  return __builtin_bit_cast(unsigned short, __float2bfloat16(x));
}
__device__ inline float bff(unsigned short u) {
  unsigned v = ((unsigned)u) << 16;
  return __builtin_bit_cast(float, v);
}
__device__ inline unsigned pack2(float x, float y) {
  return (unsigned)bfbits(x) | ((unsigned)bfbits(y) << 16);
}

__global__ __launch_bounds__(512, 2)
void fa_mfma13_kernel(const float* __restrict__ qg, const float* __restrict__ kg,
                      const float* __restrict__ vg, const int* __restrict__ cu,
                      float* __restrict__ outg) {
  // double-buffered planes: K hi [key][d] (slot ^= key&7), V^T [d][key] (slot ^= d&7)
  __shared__ unsigned short kph[2][64 * 64];
  __shared__ unsigned short vth[2][64 * 64];
  __shared__ float lsc[8 * 32];          // per-wave lane->reg bounce (corr / 1/l)

  const int bid = (int)blockIdx.x;
  const int b = bid >> 4, h = bid & 15;

  const int t0 = cu[b];
  const int L  = cu[b + 1] - t0;
  const int nt = L >> 6;                 // 64-key tiles: 2 or 4

  const int tid = (int)threadIdx.x, lane = tid & 63, w = tid >> 6;
  const int hi = lane >> 5, qj = lane & 31;
  const int qbase = w * 32;
  const bool act = (qbase < L);          // wave-uniform: L=128 -> waves 4-7 idle

  // staging maps (512 threads: each stages 8 K-floats + 8 V-floats per tile)
  const int k_key = tid >> 3, kd0 = (tid & 7) * 8;
  const int kidx  = k_key * 64 + ((((kd0 >> 3)) ^ (k_key & 7)) << 3);
  const int v_d = tid & 63, vk0 = (tid >> 6) * 8;
  const int vidx  = v_d * 64 + ((((vk0 >> 3)) ^ (v_d & 7)) << 3);

  const float* kbase = kg + (size_t)t0 * RS + h * D;
  const float* vbase = vg + (size_t)t0 * RS + h * D;

  // ---- Q fragments (B operand), hi + lo planes (registers only) ----
  bf16x8 qh[4], ql[4];
  if (act) {
    const float* qrow = qg + (size_t)(t0 + qbase + qj) * RS + h * D;
#pragma unroll
    for (int ks = 0; ks < 4; ++ks) {
      const int d0 = ks * 16 + hi * 8;
      const float4 f0 = *reinterpret_cast<const float4*>(qrow + d0);
      const float4 f1 = *reinterpret_cast<const float4*>(qrow + d0 + 4);
      const float f[8] = {f0.x, f0.y, f0.z, f0.w, f1.x, f1.y, f1.z, f1.w};
#pragma unroll
      for (int j = 0; j < 8; ++j) {
        const float x = f[j] * QSCALE;
        const unsigned short hs = bfbits(x);
        qh[ks][j] = (short)hs;
        ql[ks][j] = (short)bfbits(x - bff(hs));
      }
    }
  }

  f32x16 acc0, acc1;                     // O rows=q(reg), cols=d (n*32+qj)
#pragma unroll
  for (int r = 0; r < 16; ++r) { acc0[r] = 0.f; acc1[r] = 0.f; }
  float m = -1e30f, lsum = 0.f;

  // ---- staging: reg prefetch -> cvt -> ds_write ----
  float kf[8], vf[8];
  auto load_t = [&](int t) {
    const float* kr = kbase + (size_t)(t * 64 + k_key) * RS + kd0;
    const float4 f0 = *reinterpret_cast<const float4*>(kr);
    const float4 f1 = *reinterpret_cast<const float4*>(kr + 4);
    kf[0] = f0.x; kf[1] = f0.y; kf[2] = f0.z; kf[3] = f0.w;
    kf[4] = f1.x; kf[5] = f1.y; kf[6] = f1.z; kf[7] = f1.w;
    const float* vp = vbase + (size_t)(t * 64 + vk0) * RS + v_d;
#pragma unroll
    for (int i = 0; i < 8; ++i) vf[i] = vp[(size_t)i * RS];
  };
  auto cvt_write = [&](int buf) {
    u16x8 kh8, v8;
#pragma unroll
    for (int i = 0; i < 8; ++i) {
      kh8[i] = bfbits(kf[i]);
      v8[i]  = bfbits(vf[i]);
    }
    *reinterpret_cast<u16x8*>(&kph[buf][kidx]) = kh8;
    *reinterpret_cast<u16x8*>(&vth[buf][vidx]) = v8;
  };

  // ---- P pack (verified R8 mapping, hi plane only) ----
  const bool hib = (hi != 0);
  auto mix4 = [&](unsigned a0, unsigned a1, unsigned a2, unsigned a3) -> u32x4 {
    const unsigned t02 = hib ? a0 : a2;
    const unsigned t13 = hib ? a1 : a3;
    const unsigned c02 = (unsigned)__shfl_xor((int)t02, 32);
    const unsigned c13 = (unsigned)__shfl_xor((int)t13, 32);
    u32x4 r;
    r[0] = hib ? c02 : a0;
    r[1] = hib ? c13 : a1;
    r[2] = hib ? a2 : c02;
    r[3] = hib ? a3 : c13;
    return r;
  };
  auto build_pa = [&](const float* x) -> bf16x8 {
    return __builtin_bit_cast(bf16x8,
        mix4(pack2(x[0], x[1]), pack2(x[2], x[3]),
             pack2(x[4], x[5]), pack2(x[6], x[7])));
  };

  // ---- compute one 64-key tile ----
  auto compute = [&](int buf) {
    const unsigned short* KH = kph[buf];
    const unsigned short* VT = vth[buf];
    f32x16 sc0, sc1, tc0, tc1;
#pragma unroll
    for (int r = 0; r < 16; ++r) { sc0[r] = 0.f; sc1[r] = 0.f; tc0[r] = 0.f; tc1[r] = 0.f; }
    __builtin_amdgcn_s_setprio(1);
    // QK: 4 independent depth-4 chains (sc0/tc0 = key-half 0 qh/ql, sc1/tc1 = half 1)
#pragma unroll
    for (int ks = 0; ks < 4; ++ks) {
      const int off = (((ks * 2 + hi) ^ (qj & 7)) << 3);
      const bf16x8 khi0 = *reinterpret_cast<const bf16x8*>(&KH[qj * 64 + off]);
      const bf16x8 khi1 = *reinterpret_cast<const bf16x8*>(&KH[(32 + qj) * 64 + off]);
      sc0 = MFMA32(khi0, qh[ks], sc0);
      tc0 = MFMA32(khi0, ql[ks], tc0);
      sc1 = MFMA32(khi1, qh[ks], sc1);
      tc1 = MFMA32(khi1, ql[ks], tc1);
    }
    __builtin_amdgcn_s_setprio(0);
#pragma unroll
    for (int r = 0; r < 16; ++r) { sc0[r] += tc0[r]; sc1[r] += tc1[r]; }

    // softmax: in-register, q = qj (lane-dim); tree max, 4-way sum
    float mx[8];
#pragma unroll
    for (int i = 0; i < 8; ++i) mx[i] = fmaxf(sc0[i], sc0[i + 8]);
#pragma unroll
    for (int i = 0; i < 8; ++i) mx[i] = fmaxf(mx[i], fmaxf(sc1[i], sc1[i + 8]));
#pragma unroll
    for (int i = 0; i < 4; ++i) mx[i] = fmaxf(mx[i], mx[i + 4]);
    float tmax = fmaxf(fmaxf(mx[0], mx[1]), fmaxf(mx[2], mx[3]));
    tmax = fmaxf(tmax, __shfl_xor(tmax, 32));
    if (!__all(tmax <= m + THR)) {       // first tile + rare later
      const float newm = fmaxf(m, tmax);
      const float corr = exp2f(m - newm);
      m = newm;
      lsum *= corr;
      if (hi == 0) lsc[w * 32 + qj] = corr;    // lane-dim -> reg-dim bounce
      __builtin_amdgcn_wave_barrier();
#pragma unroll
      for (int r = 0; r < 16; ++r) {
        const float c = lsc[w * 32 + ((r & 3) + 8 * (r >> 2) + 4 * hi)];
        acc0[r] *= c; acc1[r] *= c;
      }
    }
    float s0 = 0.f, s1 = 0.f, s2 = 0.f, s3 = 0.f;
#pragma unroll
    for (int r = 0; r < 16; r += 4) {
      sc0[r]     = exp2f(sc0[r]     - m); s0 += sc0[r];
      sc0[r + 1] = exp2f(sc0[r + 1] - m); s1 += sc0[r + 1];
      sc0[r + 2] = exp2f(sc0[r + 2] - m); s2 += sc0[r + 2];
      sc0[r + 3] = exp2f(sc0[r + 3] - m); s3 += sc0[r + 3];
    }
#pragma unroll
    for (int r = 0; r < 16; r += 4) {
      sc1[r]     = exp2f(sc1[r]     - m); s0 += sc1[r];
      sc1[r + 1] = exp2f(sc1[r + 1] - m); s1 += sc1[r + 1];
      sc1[r + 2] = exp2f(sc1[r + 2] - m); s2 += sc1[r + 2];
      sc1[r + 3] = exp2f(sc1[r + 3] - m); s3 += sc1[r + 3];
    }
    float ps = (s0 + s1) + (s2 + s3);
    lsum += ps + __shfl_xor(ps, 32);

    // PV: O[q][d] via mfma32(A=P_bf16, B=V^T), 4 k-steps of 16 keys
#pragma unroll
    for (int ks2 = 0; ks2 < 4; ++ks2) {
      float px[8];
#pragma unroll
      for (int i = 0; i < 8; ++i)
        px[i] = (ks2 & 2) ? sc1[(ks2 & 1) * 8 + i] : sc0[(ks2 & 1) * 8 + i];
      const bf16x8 pah = build_pa(px);
      __builtin_amdgcn_s_setprio(1);
#pragma unroll
      for (int n = 0; n < 2; ++n) {
        const int idx = (n * 32 + qj) * 64 + (((ks2 * 2 + hi) ^ (qj & 7)) << 3);
        const bf16x8 vh = *reinterpret_cast<const bf16x8*>(&VT[idx]);
        if (n == 0) acc0 = MFMA32(pah, vh, acc0);
        else        acc1 = MFMA32(pah, vh, acc1);
      }
      __builtin_amdgcn_s_setprio(0);
    }
  };

  // ---- main loop: one barrier per tile, dbuf LDS ----
  load_t(0);
  cvt_write(0);
  if (nt > 1) load_t(1);
  asm volatile("s_waitcnt lgkmcnt(0)" ::: "memory");
  __builtin_amdgcn_s_barrier();
  asm volatile("" ::: "memory");

  for (int t = 0; t < nt; ++t) {
    const int cur = t & 1;
    if (act) compute(cur);
    if (t + 1 < nt) {
      cvt_write(cur ^ 1);
      if (t + 2 < nt) load_t(t + 2);
      asm volatile("s_waitcnt lgkmcnt(0)" ::: "memory");
      __builtin_amdgcn_s_barrier();
      asm volatile("" ::: "memory");
    }
  }

  // ---- epilogue: 1/l per q (lane-dim) -> reg-dim via LDS, store fp32 ----
  if (act) {
    if (hi == 0) lsc[w * 32 + qj] = 1.0f / lsum;
    __builtin_amdgcn_wave_barrier();
#pragma unroll
    for (int r = 0; r < 16; ++r) {
      const int row = (r & 3) + 8 * (r >> 2) + 4 * hi;
      const float li = lsc[w * 32 + row];
      float* op = outg + (size_t)(t0 + qbase + row) * RS + h * D + qj;
      op[0]  = acc0[r] * li;
      op[32] = acc1[r] * li;
    }
  }
}

extern "C" void kernel_launch(void* const* d_in, const int* in_sizes, int n_in,
                              void* d_out, int out_size, void* d_ws, size_t ws_size,
                              hipStream_t stream) {
  (void)in_sizes; (void)n_in; (void)d_ws; (void)ws_size; (void)out_size;
  const float* q  = (const float*)d_in[0];
  const float* k  = (const float*)d_in[1];
  const float* v  = (const float*)d_in[2];
  const int*   cu = (const int*)d_in[3];
  float* out = (float*)d_out;

  // one block per (seq, head): 128 * 16 = 2048 blocks, 8 waves each
  fa_mfma13_kernel<<<dim3(2048), dim3(512), 0, stream>>>(q, k, v, cu, out);
}

// Round 15
// 113.313 us; speedup vs baseline: 1.0295x; 1.0295x over previous
//
#include <hip/hip_runtime.h>
#include <hip/hip_bf16.h>

// FlashAttentionVarlen, bf16 32x32x16-MFMA flash attention, fp32 in/out.
// B=128 seqs (L in {128,256}), H=16, D=64, packed T=24576.
// R15 = R13 (113.8 us, verified best) + ONE change: __launch_bounds__(512,3).
// Toolchain fact (confirmed R8..R13): arg2 = min BLOCKS/CU -> reg caps
// (512,2)=128, (512,3)=85, (512,4)=64. R13 uses 80 VGPR -> fits 85 cap.
// 3 blocks/CU x 8 waves = 24 waves/CU (was 16), and 3 INDEPENDENT blocks
// per CU decouple the per-block barrier lockstep (R13 occupancy averaged
// only ~6 waves/CU; all pipes <30% -> wave-starved latency-bound).
// Numerics (absmax 0.0078): K bf16-hi in LDS (33 KB dbuf), Q hi+lo regs,
// QK = khi*qh + khi*ql (16 MFMA/tile), V bf16-hi, P bf16-hi (8 MFMA/tile).
// Swapped QK (mfma32(A=K,B=Q)) -> softmax lane-local in-register;
// P redistribute via __shfl_xor(32). One barrier per tile, stage-once.

using bf16x8 = __attribute__((ext_vector_type(8))) short;
using u16x8  = __attribute__((ext_vector_type(8))) unsigned short;
using u32x4  = __attribute__((ext_vector_type(4))) unsigned;
using f32x16 = __attribute__((ext_vector_type(16))) float;

#define MFMA32(a, b, c) __builtin_amdgcn_mfma_f32_32x32x16_bf16((a), (b), (c), 0, 0, 0)

constexpr int H  = 16;
constexpr int D  = 64;
constexpr int RS = H * D;                              // packed row stride (floats)
constexpr float QSCALE = 0.125f * 1.44269504088896f;   // 1/sqrt(64) * log2(e)
constexpr float THR    = 11.5f;                        // defer-max threshold (log2)

__device__ inline unsigned short bfbits(float x) {
  return __builtin_bit_cast(unsigned short, __float2bfloat16(x));
}
__device__ inline float bff(unsigned short u) {
  unsigned v = ((unsigned)u) << 16;
  return __builtin_bit_cast(float, v);
}
__device__ inline unsigned pack2(float x, float y) {
  return (unsigned)bfbits(x) | ((unsigned)bfbits(y) << 16);
}

__global__ __launch_bounds__(512, 3)
void fa_mfma14_kernel(const float* __restrict__ qg, const float* __restrict__ kg,
                      const float* __restrict__ vg, const int* __restrict__ cu,
                      float* __restrict__ outg) {
  // double-buffered planes: K hi [key][d] (slot ^= key&7), V^T [d][key] (slot ^= d&7)
  __shared__ unsigned short kph[2][64 * 64];
  __shared__ unsigned short vth[2][64 * 64];
  __shared__ float lsc[8 * 32];          // per-wave lane->reg bounce (corr / 1/l)

  const int bid = (int)blockIdx.x;
  const int b = bid >> 4, h = bid & 15;

  const int t0 = cu[b];
  const int L  = cu[b + 1] - t0;
  const int nt = L >> 6;                 // 64-key tiles: 2 or 4

  const int tid = (int)threadIdx.x, lane = tid & 63, w = tid >> 6;
  const int hi = lane >> 5, qj = lane & 31;
  const int qbase = w * 32;
  const bool act = (qbase < L);          // wave-uniform: L=128 -> waves 4-7 idle

  // staging maps (512 threads: each stages 8 K-floats + 8 V-floats per tile)
  const int k_key = tid >> 3, kd0 = (tid & 7) * 8;
  const int kidx  = k_key * 64 + ((((kd0 >> 3)) ^ (k_key & 7)) << 3);
  const int v_d = tid & 63, vk0 = (tid >> 6) * 8;
  const int vidx  = v_d * 64 + ((((vk0 >> 3)) ^ (v_d & 7)) << 3);

  const float* kbase = kg + (size_t)t0 * RS + h * D;
  const float* vbase = vg + (size_t)t0 * RS + h * D;

  // ---- Q fragments (B operand), hi + lo planes (registers only) ----
  bf16x8 qh[4], ql[4];
  if (act) {
    const float* qrow = qg + (size_t)(t0 + qbase + qj) * RS + h * D;
#pragma unroll
    for (int ks = 0; ks < 4; ++ks) {
      const int d0 = ks * 16 + hi * 8;
      const float4 f0 = *reinterpret_cast<const float4*>(qrow + d0);
      const float4 f1 = *reinterpret_cast<const float4*>(qrow + d0 + 4);
      const float f[8] = {f0.x, f0.y, f0.z, f0.w, f1.x, f1.y, f1.z, f1.w};
#pragma unroll
      for (int j = 0; j < 8; ++j) {
        const float x = f[j] * QSCALE;
        const unsigned short hs = bfbits(x);
        qh[ks][j] = (short)hs;
        ql[ks][j] = (short)bfbits(x - bff(hs));
      }
    }
  }

  f32x16 acc0, acc1;                     // O rows=q(reg), cols=d (n*32+qj)
#pragma unroll
  for (int r = 0; r < 16; ++r) { acc0[r] = 0.f; acc1[r] = 0.f; }
  float m = -1e30f, lsum = 0.f;

  // ---- staging: reg prefetch -> cvt -> ds_write ----
  float kf[8], vf[8];
  auto load_t = [&](int t) {
    const float* kr = kbase + (size_t)(t * 64 + k_key) * RS + kd0;
    const float4 f0 = *reinterpret_cast<const float4*>(kr);
    const float4 f1 = *reinterpret_cast<const float4*>(kr + 4);
    kf[0] = f0.x; kf[1] = f0.y; kf[2] = f0.z; kf[3] = f0.w;
    kf[4] = f1.x; kf[5] = f1.y; kf[6] = f1.z; kf[7] = f1.w;
    const float* vp = vbase + (size_t)(t * 64 + vk0) * RS + v_d;
#pragma unroll
    for (int i = 0; i < 8; ++i) vf[i] = vp[(size_t)i * RS];
  };
  auto cvt_write = [&](int buf) {
    u16x8 kh8, v8;
#pragma unroll
    for (int i = 0; i < 8; ++i) {
      kh8[i] = bfbits(kf[i]);
      v8[i]  = bfbits(vf[i]);
    }
    *reinterpret_cast<u16x8*>(&kph[buf][kidx]) = kh8;
    *reinterpret_cast<u16x8*>(&vth[buf][vidx]) = v8;
  };

  // ---- P pack (verified R8 mapping, hi plane only) ----
  const bool hib = (hi != 0);
  auto mix4 = [&](unsigned a0, unsigned a1, unsigned a2, unsigned a3) -> u32x4 {
    const unsigned t02 = hib ? a0 : a2;
    const unsigned t13 = hib ? a1 : a3;
    const unsigned c02 = (unsigned)__shfl_xor((int)t02, 32);
    const unsigned c13 = (unsigned)__shfl_xor((int)t13, 32);
    u32x4 r;
    r[0] = hib ? c02 : a0;
    r[1] = hib ? c13 : a1;
    r[2] = hib ? a2 : c02;
    r[3] = hib ? a3 : c13;
    return r;
  };
  auto build_pa = [&](const float* x) -> bf16x8 {
    return __builtin_bit_cast(bf16x8,
        mix4(pack2(x[0], x[1]), pack2(x[2], x[3]),
             pack2(x[4], x[5]), pack2(x[6], x[7])));
  };

  // ---- compute one 64-key tile ----
  auto compute = [&](int buf) {
    const unsigned short* KH = kph[buf];
    const unsigned short* VT = vth[buf];
    f32x16 sc0, sc1;
#pragma unroll
    for (int r = 0; r < 16; ++r) { sc0[r] = 0.f; sc1[r] = 0.f; }
    __builtin_amdgcn_s_setprio(1);
#pragma unroll
    for (int kt = 0; kt < 2; ++kt) {
#pragma unroll
      for (int ks = 0; ks < 4; ++ks) {
        const int idx = (kt * 32 + qj) * 64 + (((ks * 2 + hi) ^ (qj & 7)) << 3);
        const bf16x8 khi = *reinterpret_cast<const bf16x8*>(&KH[idx]);
        if (kt == 0) {
          sc0 = MFMA32(khi, qh[ks], sc0);
          sc0 = MFMA32(khi, ql[ks], sc0);
        } else {
          sc1 = MFMA32(khi, qh[ks], sc1);
          sc1 = MFMA32(khi, ql[ks], sc1);
        }
      }
    }
    __builtin_amdgcn_s_setprio(0);

    // softmax: in-register, q = qj (lane-dim); tree max, 4-way sum
    float mx[8];
#pragma unroll
    for (int i = 0; i < 8; ++i) mx[i] = fmaxf(sc0[i], sc0[i + 8]);
#pragma unroll
    for (int i = 0; i < 8; ++i) mx[i] = fmaxf(mx[i], fmaxf(sc1[i], sc1[i + 8]));
#pragma unroll
    for (int i = 0; i < 4; ++i) mx[i] = fmaxf(mx[i], mx[i + 4]);
    float tmax = fmaxf(fmaxf(mx[0], mx[1]), fmaxf(mx[2], mx[3]));
    tmax = fmaxf(tmax, __shfl_xor(tmax, 32));
    if (!__all(tmax <= m + THR)) {       // first tile + rare later
      const float newm = fmaxf(m, tmax);
      const float corr = exp2f(m - newm);
      m = newm;
      lsum *= corr;
      if (hi == 0) lsc[w * 32 + qj] = corr;    // lane-dim -> reg-dim bounce
      __builtin_amdgcn_wave_barrier();
#pragma unroll
      for (int r = 0; r < 16; ++r) {
        const float c = lsc[w * 32 + ((r & 3) + 8 * (r >> 2) + 4 * hi)];
        acc0[r] *= c; acc1[r] *= c;
      }
    }
    float s0 = 0.f, s1 = 0.f, s2 = 0.f, s3 = 0.f;
#pragma unroll
    for (int r = 0; r < 16; r += 4) {
      sc0[r]     = exp2f(sc0[r]     - m); s0 += sc0[r];
      sc0[r + 1] = exp2f(sc0[r + 1] - m); s1 += sc0[r + 1];
      sc0[r + 2] = exp2f(sc0[r + 2] - m); s2 += sc0[r + 2];
      sc0[r + 3] = exp2f(sc0[r + 3] - m); s3 += sc0[r + 3];
    }
#pragma unroll
    for (int r = 0; r < 16; r += 4) {
      sc1[r]     = exp2f(sc1[r]     - m); s0 += sc1[r];
      sc1[r + 1] = exp2f(sc1[r + 1] - m); s1 += sc1[r + 1];
      sc1[r + 2] = exp2f(sc1[r + 2] - m); s2 += sc1[r + 2];
      sc1[r + 3] = exp2f(sc1[r + 3] - m); s3 += sc1[r + 3];
    }
    float ps = (s0 + s1) + (s2 + s3);
    lsum += ps + __shfl_xor(ps, 32);

    // PV: O[q][d] via mfma32(A=P_bf16, B=V^T), 4 k-steps of 16 keys
#pragma unroll
    for (int ks2 = 0; ks2 < 4; ++ks2) {
      float px[8];
#pragma unroll
      for (int i = 0; i < 8; ++i)
        px[i] = (ks2 & 2) ? sc1[(ks2 & 1) * 8 + i] : sc0[(ks2 & 1) * 8 + i];
      const bf16x8 pah = build_pa(px);
      __builtin_amdgcn_s_setprio(1);
#pragma unroll
      for (int n = 0; n < 2; ++n) {
        const int idx = (n * 32 + qj) * 64 + (((ks2 * 2 + hi) ^ (qj & 7)) << 3);
        const bf16x8 vh = *reinterpret_cast<const bf16x8*>(&VT[idx]);
        if (n == 0) acc0 = MFMA32(pah, vh, acc0);
        else        acc1 = MFMA32(pah, vh, acc1);
      }
      __builtin_amdgcn_s_setprio(0);
    }
  };

  // ---- main loop: one barrier per tile, dbuf LDS ----
  load_t(0);
  cvt_write(0);
  if (nt > 1) load_t(1);
  asm volatile("s_waitcnt lgkmcnt(0)" ::: "memory");
  __builtin_amdgcn_s_barrier();
  asm volatile("" ::: "memory");

  for (int t = 0; t < nt; ++t) {
    const int cur = t & 1;
    if (act) compute(cur);
    if (t + 1 < nt) {
      cvt_write(cur ^ 1);
      if (t + 2 < nt) load_t(t + 2);
      asm volatile("s_waitcnt lgkmcnt(0)" ::: "memory");
      __builtin_amdgcn_s_barrier();
      asm volatile("" ::: "memory");
    }
  }

  // ---- epilogue: 1/l per q (lane-dim) -> reg-dim via LDS, store fp32 ----
  if (act) {
    if (hi == 0) lsc[w * 32 + qj] = 1.0f / lsum;
    __builtin_amdgcn_wave_barrier();
#pragma unroll
    for (int r = 0; r < 16; ++r) {
      const int row = (r & 3) + 8 * (r >> 2) + 4 * hi;
      const float li = lsc[w * 32 + row];
      float* op = outg + (size_t)(t0 + qbase + row) * RS + h * D + qj;
      op[0]  = acc0[r] * li;
      op[32] = acc1[r] * li;
    }
  }
}

extern "C" void kernel_launch(void* const* d_in, const int* in_sizes, int n_in,
                              void* d_out, int out_size, void* d_ws, size_t ws_size,
                              hipStream_t stream) {
  (void)in_sizes; (void)n_in; (void)d_ws; (void)ws_size; (void)out_size;
  const float* q  = (const float*)d_in[0];
  const float* k  = (const float*)d_in[1];
  const float* v  = (const float*)d_in[2];
  const int*   cu = (const int*)d_in[3];
  float* out = (float*)d_out;

  // one block per (seq, head): 128 * 16 = 2048 blocks, 8 waves each
  fa_mfma14_kernel<<<dim3(2048), dim3(512), 0, stream>>>(q, k, v, cu, out);
}

// Round 16
// 112.737 us; speedup vs baseline: 1.0347x; 1.0051x over previous
//
#include <hip/hip_runtime.h>
#include <hip/hip_bf16.h>

// FlashAttentionVarlen, bf16 32x32x16-MFMA flash attention, fp32 in/out.
// B=128 seqs (L in {128,256}), H=16, D=64, packed T=24576.
// R16 = R13/R15 compute (byte-identical numerics, absmax 0.0078) + ONE
// structural change: PERSISTENT WORK-STEALING shell. 768 blocks (3/CU via
// (512,3): 85-reg cap, fits 80-reg body; LDS 33KB x 3 = 101KB <= 160KB),
// each block loops: atomicAdd on a global counter -> (b,h) item 0..2047.
// Rationale: R15 showed raising the residency CAP does nothing (occupancy
// pinned ~6 waves/CU) -> suspect per-block dispatch/prologue serialization
// + heterogeneous-length tail. Persistence pins residency for the whole
// kernel, removes dispatch gaps, and work-stealing balances L=128/L=256.
// Counter = first 4 bytes of d_ws, zeroed via hipMemsetAsync each launch.

using bf16x8 = __attribute__((ext_vector_type(8))) short;
using u16x8  = __attribute__((ext_vector_type(8))) unsigned short;
using u32x4  = __attribute__((ext_vector_type(4))) unsigned;
using f32x16 = __attribute__((ext_vector_type(16))) float;

#define MFMA32(a, b, c) __builtin_amdgcn_mfma_f32_32x32x16_bf16((a), (b), (c), 0, 0, 0)

constexpr int H  = 16;
constexpr int D  = 64;
constexpr int RS = H * D;                              // packed row stride (floats)
constexpr int NITEMS = 128 * 16;                       // (b,h) work items
constexpr float QSCALE = 0.125f * 1.44269504088896f;   // 1/sqrt(64) * log2(e)
constexpr float THR    = 11.5f;                        // defer-max threshold (log2)

__device__ inline unsigned short bfbits(float x) {
  return __builtin_bit_cast(unsigned short, __float2bfloat16(x));
}
__device__ inline float bff(unsigned short u) {
  unsigned v = ((unsigned)u) << 16;
  return __builtin_bit_cast(float, v);
}
__device__ inline unsigned pack2(float x, float y) {
  return (unsigned)bfbits(x) | ((unsigned)bfbits(y) << 16);
}

__global__ __launch_bounds__(512, 3)
void fa_persist_kernel(const float* __restrict__ qg, const float* __restrict__ kg,
                       const float* __restrict__ vg, const int* __restrict__ cu,
                       float* __restrict__ outg, int* __restrict__ ctr) {
  // double-buffered planes: K hi [key][d] (slot ^= key&7), V^T [d][key] (slot ^= d&7)
  __shared__ unsigned short kph[2][64 * 64];
  __shared__ unsigned short vth[2][64 * 64];
  __shared__ float lsc[8 * 32];          // per-wave lane->reg bounce (corr / 1/l)
  __shared__ int item_s;

  const int tid = (int)threadIdx.x, lane = tid & 63, w = tid >> 6;
  const int hi = lane >> 5, qj = lane & 31;
  const int qbase = w * 32;
  const bool hib = (hi != 0);

  // staging maps (512 threads: each stages 8 K-floats + 8 V-floats per tile)
  const int k_key = tid >> 3, kd0 = (tid & 7) * 8;
  const int kidx  = k_key * 64 + ((((kd0 >> 3)) ^ (k_key & 7)) << 3);
  const int v_d = tid & 63, vk0 = (tid >> 6) * 8;
  const int vidx  = v_d * 64 + ((((vk0 >> 3)) ^ (v_d & 7)) << 3);

  for (;;) {
    // ---- grab next (b,h) item (one atomic per block-item) ----
    if (tid == 0) item_s = atomicAdd(ctr, 1);
    __syncthreads();                     // item_s visible to all
    const int item = item_s;
    __syncthreads();                     // all read before next overwrite
    if (item >= NITEMS) break;           // block-uniform exit

    const int b = item >> 4, h = item & 15;
    const int t0 = cu[b];
    const int L  = cu[b + 1] - t0;
    const int nt = L >> 6;               // 64-key tiles: 2 or 4
    const bool act = (qbase < L);        // wave-uniform: L=128 -> waves 4-7 idle

    const float* kbase = kg + (size_t)t0 * RS + h * D;
    const float* vbase = vg + (size_t)t0 * RS + h * D;

    // ---- Q fragments (B operand), hi + lo planes (registers only) ----
    bf16x8 qh[4], ql[4];
    if (act) {
      const float* qrow = qg + (size_t)(t0 + qbase + qj) * RS + h * D;
#pragma unroll
      for (int ks = 0; ks < 4; ++ks) {
        const int d0 = ks * 16 + hi * 8;
        const float4 f0 = *reinterpret_cast<const float4*>(qrow + d0);
        const float4 f1 = *reinterpret_cast<const float4*>(qrow + d0 + 4);
        const float f[8] = {f0.x, f0.y, f0.z, f0.w, f1.x, f1.y, f1.z, f1.w};
#pragma unroll
        for (int j = 0; j < 8; ++j) {
          const float x = f[j] * QSCALE;
          const unsigned short hs = bfbits(x);
          qh[ks][j] = (short)hs;
          ql[ks][j] = (short)bfbits(x - bff(hs));
        }
      }
    }

    f32x16 acc0, acc1;                   // O rows=q(reg), cols=d (n*32+qj)
#pragma unroll
    for (int r = 0; r < 16; ++r) { acc0[r] = 0.f; acc1[r] = 0.f; }
    float m = -1e30f, lsum = 0.f;

    // ---- staging: reg prefetch -> cvt -> ds_write ----
    float kf[8], vf[8];
    auto load_t = [&](int t) {
      const float* kr = kbase + (size_t)(t * 64 + k_key) * RS + kd0;
      const float4 f0 = *reinterpret_cast<const float4*>(kr);
      const float4 f1 = *reinterpret_cast<const float4*>(kr + 4);
      kf[0] = f0.x; kf[1] = f0.y; kf[2] = f0.z; kf[3] = f0.w;
      kf[4] = f1.x; kf[5] = f1.y; kf[6] = f1.z; kf[7] = f1.w;
      const float* vp = vbase + (size_t)(t * 64 + vk0) * RS + v_d;
#pragma unroll
      for (int i = 0; i < 8; ++i) vf[i] = vp[(size_t)i * RS];
    };
    auto cvt_write = [&](int buf) {
      u16x8 kh8, v8;
#pragma unroll
      for (int i = 0; i < 8; ++i) {
        kh8[i] = bfbits(kf[i]);
        v8[i]  = bfbits(vf[i]);
      }
      *reinterpret_cast<u16x8*>(&kph[buf][kidx]) = kh8;
      *reinterpret_cast<u16x8*>(&vth[buf][vidx]) = v8;
    };

    auto mix4 = [&](unsigned a0, unsigned a1, unsigned a2, unsigned a3) -> u32x4 {
      const unsigned t02 = hib ? a0 : a2;
      const unsigned t13 = hib ? a1 : a3;
      const unsigned c02 = (unsigned)__shfl_xor((int)t02, 32);
      const unsigned c13 = (unsigned)__shfl_xor((int)t13, 32);
      u32x4 r;
      r[0] = hib ? c02 : a0;
      r[1] = hib ? c13 : a1;
      r[2] = hib ? a2 : c02;
      r[3] = hib ? a3 : c13;
      return r;
    };
    auto build_pa = [&](const float* x) -> bf16x8 {
      return __builtin_bit_cast(bf16x8,
          mix4(pack2(x[0], x[1]), pack2(x[2], x[3]),
               pack2(x[4], x[5]), pack2(x[6], x[7])));
    };

    // ---- compute one 64-key tile (identical to R13) ----
    auto compute = [&](int buf) {
      const unsigned short* KH = kph[buf];
      const unsigned short* VT = vth[buf];
      f32x16 sc0, sc1;
#pragma unroll
      for (int r = 0; r < 16; ++r) { sc0[r] = 0.f; sc1[r] = 0.f; }
      __builtin_amdgcn_s_setprio(1);
#pragma unroll
      for (int kt = 0; kt < 2; ++kt) {
#pragma unroll
        for (int ks = 0; ks < 4; ++ks) {
          const int idx = (kt * 32 + qj) * 64 + (((ks * 2 + hi) ^ (qj & 7)) << 3);
          const bf16x8 khi = *reinterpret_cast<const bf16x8*>(&KH[idx]);
          if (kt == 0) {
            sc0 = MFMA32(khi, qh[ks], sc0);
            sc0 = MFMA32(khi, ql[ks], sc0);
          } else {
            sc1 = MFMA32(khi, qh[ks], sc1);
            sc1 = MFMA32(khi, ql[ks], sc1);
          }
        }
      }
      __builtin_amdgcn_s_setprio(0);

      float mx[8];
#pragma unroll
      for (int i = 0; i < 8; ++i) mx[i] = fmaxf(sc0[i], sc0[i + 8]);
#pragma unroll
      for (int i = 0; i < 8; ++i) mx[i] = fmaxf(mx[i], fmaxf(sc1[i], sc1[i + 8]));
#pragma unroll
      for (int i = 0; i < 4; ++i) mx[i] = fmaxf(mx[i], mx[i + 4]);
      float tmax = fmaxf(fmaxf(mx[0], mx[1]), fmaxf(mx[2], mx[3]));
      tmax = fmaxf(tmax, __shfl_xor(tmax, 32));
      if (!__all(tmax <= m + THR)) {     // first tile + rare later
        const float newm = fmaxf(m, tmax);
        const float corr = exp2f(m - newm);
        m = newm;
        lsum *= corr;
        if (hi == 0) lsc[w * 32 + qj] = corr;  // lane-dim -> reg-dim bounce
        __builtin_amdgcn_wave_barrier();
#pragma unroll
        for (int r = 0; r < 16; ++r) {
          const float c = lsc[w * 32 + ((r & 3) + 8 * (r >> 2) + 4 * hi)];
          acc0[r] *= c; acc1[r] *= c;
        }
      }
      float s0 = 0.f, s1 = 0.f, s2 = 0.f, s3 = 0.f;
#pragma unroll
      for (int r = 0; r < 16; r += 4) {
        sc0[r]     = exp2f(sc0[r]     - m); s0 += sc0[r];
        sc0[r + 1] = exp2f(sc0[r + 1] - m); s1 += sc0[r + 1];
        sc0[r + 2] = exp2f(sc0[r + 2] - m); s2 += sc0[r + 2];
        sc0[r + 3] = exp2f(sc0[r + 3] - m); s3 += sc0[r + 3];
      }
#pragma unroll
      for (int r = 0; r < 16; r += 4) {
        sc1[r]     = exp2f(sc1[r]     - m); s0 += sc1[r];
        sc1[r + 1] = exp2f(sc1[r + 1] - m); s1 += sc1[r + 1];
        sc1[r + 2] = exp2f(sc1[r + 2] - m); s2 += sc1[r + 2];
        sc1[r + 3] = exp2f(sc1[r + 3] - m); s3 += sc1[r + 3];
      }
      float ps = (s0 + s1) + (s2 + s3);
      lsum += ps + __shfl_xor(ps, 32);

#pragma unroll
      for (int ks2 = 0; ks2 < 4; ++ks2) {
        float px[8];
#pragma unroll
        for (int i = 0; i < 8; ++i)
          px[i] = (ks2 & 2) ? sc1[(ks2 & 1) * 8 + i] : sc0[(ks2 & 1) * 8 + i];
        const bf16x8 pah = build_pa(px);
        __builtin_amdgcn_s_setprio(1);
#pragma unroll
        for (int n = 0; n < 2; ++n) {
          const int idx = (n * 32 + qj) * 64 + (((ks2 * 2 + hi) ^ (qj & 7)) << 3);
          const bf16x8 vh = *reinterpret_cast<const bf16x8*>(&VT[idx]);
          if (n == 0) acc0 = MFMA32(pah, vh, acc0);
          else        acc1 = MFMA32(pah, vh, acc1);
        }
        __builtin_amdgcn_s_setprio(0);
      }
    };

    // ---- main loop: one barrier per tile, dbuf LDS ----
    load_t(0);
    cvt_write(0);
    if (nt > 1) load_t(1);
    asm volatile("s_waitcnt lgkmcnt(0)" ::: "memory");
    __builtin_amdgcn_s_barrier();
    asm volatile("" ::: "memory");

    for (int t = 0; t < nt; ++t) {
      const int cur = t & 1;
      if (act) compute(cur);
      if (t + 1 < nt) {
        cvt_write(cur ^ 1);
        if (t + 2 < nt) load_t(t + 2);
        asm volatile("s_waitcnt lgkmcnt(0)" ::: "memory");
        __builtin_amdgcn_s_barrier();
        asm volatile("" ::: "memory");
      }
    }

    // ---- epilogue: 1/l per q (lane-dim) -> reg-dim via LDS, store fp32 ----
    if (act) {
      if (hi == 0) lsc[w * 32 + qj] = 1.0f / lsum;
      __builtin_amdgcn_wave_barrier();
#pragma unroll
      for (int r = 0; r < 16; ++r) {
        const int row = (r & 3) + 8 * (r >> 2) + 4 * hi;
        const float li = lsc[w * 32 + row];
        float* op = outg + (size_t)(t0 + qbase + row) * RS + h * D + qj;
        op[0]  = acc0[r] * li;
        op[32] = acc1[r] * li;
      }
    }
    // next item's grab __syncthreads orders LDS reuse across items
  }
}

extern "C" void kernel_launch(void* const* d_in, const int* in_sizes, int n_in,
                              void* d_out, int out_size, void* d_ws, size_t ws_size,
                              hipStream_t stream) {
  (void)in_sizes; (void)n_in; (void)ws_size; (void)out_size;
  const float* q  = (const float*)d_in[0];
  const float* k  = (const float*)d_in[1];
  const float* v  = (const float*)d_in[2];
  const int*   cu = (const int*)d_in[3];
  float* out = (float*)d_out;
  int*   ctr = (int*)d_ws;

  hipMemsetAsync(ctr, 0, sizeof(int), stream);   // work counter = 0 each launch
  // persistent: 3 blocks/CU x 256 CUs = 768 blocks, work-steal 2048 items
  fa_persist_kernel<<<dim3(768), dim3(512), 0, stream>>>(q, k, v, cu, out, ctr);
}

// Round 17
// 111.716 us; speedup vs baseline: 1.0442x; 1.0091x over previous
//
#include <hip/hip_runtime.h>
#include <hip/hip_bf16.h>

// FlashAttentionVarlen, bf16 32x32x16-MFMA flash attention, fp32 in/out.
// B=128 seqs (L in {128,256}), H=16, D=64, packed T=24576.
// R17 = R16 persistent shell + INSTRUCTION DIET (numerics byte-identical,
// absmax 0.0078). Diagnosis: per-SIMD issue-bound on a VALU-heavy mix
// (~1000 VALU instr/wave-tile, half of it LDS address recomputation).
// Changes: (1) swizzle algebra folded: idx(kt,ks) = BASE_kt ^ (ks<<4)
// with BASE shared by QK and PV reads -> 1 VALU/access (was ~4);
// (2) tile loop fully unrolled (nt in {2,4}) -> compile-time LDS buffer
// bases; (3) (512,2) for register headroom under the unroll (grid 512).
// Numerics: K bf16-hi in LDS (33 KB dbuf), Q hi+lo regs (QK = khi*qh +
// khi*ql), V bf16-hi, P bf16-hi; swapped QK; in-register softmax;
// P redistribute via __shfl_xor(32); one barrier per tile.

using bf16x8 = __attribute__((ext_vector_type(8))) short;
using u16x8  = __attribute__((ext_vector_type(8))) unsigned short;
using u32x4  = __attribute__((ext_vector_type(4))) unsigned;
using f32x16 = __attribute__((ext_vector_type(16))) float;

#define MFMA32(a, b, c) __builtin_amdgcn_mfma_f32_32x32x16_bf16((a), (b), (c), 0, 0, 0)

constexpr int H  = 16;
constexpr int D  = 64;
constexpr int RS = H * D;                              // packed row stride (floats)
constexpr int NITEMS = 128 * 16;                       // (b,h) work items
constexpr float QSCALE = 0.125f * 1.44269504088896f;   // 1/sqrt(64) * log2(e)
constexpr float THR    = 11.5f;                        // defer-max threshold (log2)

__device__ inline unsigned short bfbits(float x) {
  return __builtin_bit_cast(unsigned short, __float2bfloat16(x));
}
__device__ inline float bff(unsigned short u) {
  unsigned v = ((unsigned)u) << 16;
  return __builtin_bit_cast(float, v);
}
__device__ inline unsigned pack2(float x, float y) {
  return (unsigned)bfbits(x) | ((unsigned)bfbits(y) << 16);
}

__global__ __launch_bounds__(512, 2)
void fa_persist3_kernel(const float* __restrict__ qg, const float* __restrict__ kg,
                        const float* __restrict__ vg, const int* __restrict__ cu,
                        float* __restrict__ outg, int* __restrict__ ctr) {
  // double-buffered planes: K hi [key][d] (slot ^= key&7), V^T [d][key] (slot ^= d&7)
  __shared__ unsigned short kph[2][64 * 64];
  __shared__ unsigned short vth[2][64 * 64];
  __shared__ float lsc[8 * 32];          // per-wave lane->reg bounce (corr / 1/l)
  __shared__ int item_s;

  const int tid = (int)threadIdx.x, lane = tid & 63, w = tid >> 6;
  const int hi = lane >> 5, qj = lane & 31;
  const int qbase = w * 32;
  const bool hib = (hi != 0);

  // Folded swizzle bases: idx(row=kt*32+qj, slot=ks*2+hi) = BASE_kt ^ (ks<<4)
  //   ((ks<<1)|hi) ^ m7 = (ks<<1) ^ (hi^m7); XOR bits (3..5) < row stride 64.
  const int m7   = qj & 7;
  const int boff = (hi ^ m7) << 3;
  const int KA0  = qj * 64 + boff;         // kt/n = 0 (shared by QK and PV)
  const int KA1  = (32 + qj) * 64 + boff;  // kt/n = 1

  // staging maps (512 threads: each stages 8 K-floats + 8 V-floats per tile)
  const int k_key = tid >> 3, kd0 = (tid & 7) * 8;
  const int kidx  = k_key * 64 + ((((kd0 >> 3)) ^ (k_key & 7)) << 3);
  const int v_d = tid & 63, vk0 = (tid >> 6) * 8;
  const int vidx  = v_d * 64 + ((((vk0 >> 3)) ^ (v_d & 7)) << 3);

  for (;;) {
    // ---- grab next (b,h) item ----
    if (tid == 0) item_s = atomicAdd(ctr, 1);
    __syncthreads();
    const int item = item_s;
    __syncthreads();
    if (item >= NITEMS) break;           // block-uniform exit

    const int b = item >> 4, h = item & 15;
    const int t0 = cu[b];
    const int L  = cu[b + 1] - t0;
    const int nt = L >> 6;               // 2 or 4
    const bool act = (qbase < L);        // wave-uniform

    const float* kbase = kg + (size_t)t0 * RS + h * D;
    const float* vbase = vg + (size_t)t0 * RS + h * D;

    // ---- Q fragments (B operand), hi + lo planes (registers only) ----
    bf16x8 qh[4], ql[4];
    if (act) {
      const float* qrow = qg + (size_t)(t0 + qbase + qj) * RS + h * D;
#pragma unroll
      for (int ks = 0; ks < 4; ++ks) {
        const int d0 = ks * 16 + hi * 8;
        const float4 f0 = *reinterpret_cast<const float4*>(qrow + d0);
        const float4 f1 = *reinterpret_cast<const float4*>(qrow + d0 + 4);
        const float f[8] = {f0.x, f0.y, f0.z, f0.w, f1.x, f1.y, f1.z, f1.w};
#pragma unroll
        for (int j = 0; j < 8; ++j) {
          const float x = f[j] * QSCALE;
          const unsigned short hs = bfbits(x);
          qh[ks][j] = (short)hs;
          ql[ks][j] = (short)bfbits(x - bff(hs));
        }
      }
    }

    f32x16 acc0, acc1;
#pragma unroll
    for (int r = 0; r < 16; ++r) { acc0[r] = 0.f; acc1[r] = 0.f; }
    float m = -1e30f, lsum = 0.f;

    // ---- staging: reg prefetch -> cvt -> ds_write ----
    float kf[8], vf[8];
    auto load_t = [&](int t) {
      const float* kr = kbase + (size_t)(t * 64 + k_key) * RS + kd0;
      const float4 f0 = *reinterpret_cast<const float4*>(kr);
      const float4 f1 = *reinterpret_cast<const float4*>(kr + 4);
      kf[0] = f0.x; kf[1] = f0.y; kf[2] = f0.z; kf[3] = f0.w;
      kf[4] = f1.x; kf[5] = f1.y; kf[6] = f1.z; kf[7] = f1.w;
      const float* vp = vbase + (size_t)(t * 64 + vk0) * RS + v_d;
#pragma unroll
      for (int i = 0; i < 8; ++i) vf[i] = vp[(size_t)i * RS];
    };
    auto cvt_write = [&](unsigned short* KP, unsigned short* VP) {
      u16x8 kh8, v8;
#pragma unroll
      for (int i = 0; i < 8; ++i) {
        kh8[i] = bfbits(kf[i]);
        v8[i]  = bfbits(vf[i]);
      }
      *reinterpret_cast<u16x8*>(KP + kidx) = kh8;
      *reinterpret_cast<u16x8*>(VP + vidx) = v8;
    };

    auto mix4 = [&](unsigned a0, unsigned a1, unsigned a2, unsigned a3) -> u32x4 {
      const unsigned t02 = hib ? a0 : a2;
      const unsigned t13 = hib ? a1 : a3;
      const unsigned c02 = (unsigned)__shfl_xor((int)t02, 32);
      const unsigned c13 = (unsigned)__shfl_xor((int)t13, 32);
      u32x4 r;
      r[0] = hib ? c02 : a0;
      r[1] = hib ? c13 : a1;
      r[2] = hib ? a2 : c02;
      r[3] = hib ? a3 : c13;
      return r;
    };
    auto build_pa = [&](const float* x) -> bf16x8 {
      return __builtin_bit_cast(bf16x8,
          mix4(pack2(x[0], x[1]), pack2(x[2], x[3]),
               pack2(x[4], x[5]), pack2(x[6], x[7])));
    };

    // ---- compute one 64-key tile (compile-time buffer pointers) ----
    auto compute = [&](const unsigned short* KH, const unsigned short* VT) {
      f32x16 sc0, sc1;
#pragma unroll
      for (int r = 0; r < 16; ++r) { sc0[r] = 0.f; sc1[r] = 0.f; }
      __builtin_amdgcn_s_setprio(1);
#pragma unroll
      for (int ks = 0; ks < 4; ++ks) {
        const bf16x8 k0 = *reinterpret_cast<const bf16x8*>(&KH[KA0 ^ (ks << 4)]);
        sc0 = MFMA32(k0, qh[ks], sc0);
        sc0 = MFMA32(k0, ql[ks], sc0);
      }
#pragma unroll
      for (int ks = 0; ks < 4; ++ks) {
        const bf16x8 k1 = *reinterpret_cast<const bf16x8*>(&KH[KA1 ^ (ks << 4)]);
        sc1 = MFMA32(k1, qh[ks], sc1);
        sc1 = MFMA32(k1, ql[ks], sc1);
      }
      __builtin_amdgcn_s_setprio(0);

      // softmax: in-register, q = qj (lane-dim); tree max, 4-way sum
      float mx[8];
#pragma unroll
      for (int i = 0; i < 8; ++i) mx[i] = fmaxf(sc0[i], sc0[i + 8]);
#pragma unroll
      for (int i = 0; i < 8; ++i) mx[i] = fmaxf(mx[i], fmaxf(sc1[i], sc1[i + 8]));
#pragma unroll
      for (int i = 0; i < 4; ++i) mx[i] = fmaxf(mx[i], mx[i + 4]);
      float tmax = fmaxf(fmaxf(mx[0], mx[1]), fmaxf(mx[2], mx[3]));
      tmax = fmaxf(tmax, __shfl_xor(tmax, 32));
      if (!__all(tmax <= m + THR)) {     // first tile + rare later
        const float newm = fmaxf(m, tmax);
        const float corr = exp2f(m - newm);
        m = newm;
        lsum *= corr;
        if (hi == 0) lsc[w * 32 + qj] = corr;  // lane-dim -> reg-dim bounce
        __builtin_amdgcn_wave_barrier();
#pragma unroll
        for (int r = 0; r < 16; ++r) {
          const float c = lsc[w * 32 + ((r & 3) + 8 * (r >> 2) + 4 * hi)];
          acc0[r] *= c; acc1[r] *= c;
        }
      }
      float s0 = 0.f, s1 = 0.f, s2 = 0.f, s3 = 0.f;
#pragma unroll
      for (int r = 0; r < 16; r += 4) {
        sc0[r]     = exp2f(sc0[r]     - m); s0 += sc0[r];
        sc0[r + 1] = exp2f(sc0[r + 1] - m); s1 += sc0[r + 1];
        sc0[r + 2] = exp2f(sc0[r + 2] - m); s2 += sc0[r + 2];
        sc0[r + 3] = exp2f(sc0[r + 3] - m); s3 += sc0[r + 3];
      }
#pragma unroll
      for (int r = 0; r < 16; r += 4) {
        sc1[r]     = exp2f(sc1[r]     - m); s0 += sc1[r];
        sc1[r + 1] = exp2f(sc1[r + 1] - m); s1 += sc1[r + 1];
        sc1[r + 2] = exp2f(sc1[r + 2] - m); s2 += sc1[r + 2];
        sc1[r + 3] = exp2f(sc1[r + 3] - m); s3 += sc1[r + 3];
      }
      float ps = (s0 + s1) + (s2 + s3);
      lsum += ps + __shfl_xor(ps, 32);

      // PV: O[q][d] via mfma32(A=P_bf16, B=V^T); bases shared with QK
#pragma unroll
      for (int ks2 = 0; ks2 < 4; ++ks2) {
        float px[8];
#pragma unroll
        for (int i = 0; i < 8; ++i)
          px[i] = (ks2 & 2) ? sc1[(ks2 & 1) * 8 + i] : sc0[(ks2 & 1) * 8 + i];
        const bf16x8 pah = build_pa(px);
        __builtin_amdgcn_s_setprio(1);
        const bf16x8 v0 = *reinterpret_cast<const bf16x8*>(&VT[KA0 ^ (ks2 << 4)]);
        const bf16x8 v1 = *reinterpret_cast<const bf16x8*>(&VT[KA1 ^ (ks2 << 4)]);
        acc0 = MFMA32(pah, v0, acc0);
        acc1 = MFMA32(pah, v1, acc1);
        __builtin_amdgcn_s_setprio(0);
      }
    };

#define LGKM_BARRIER()                                    \
    asm volatile("s_waitcnt lgkmcnt(0)" ::: "memory");    \
    __builtin_amdgcn_s_barrier();                         \
    asm volatile("" ::: "memory")

    // ---- fully unrolled tile schedule (nt = 2 or 4) ----
    load_t(0);
    cvt_write(kph[0], vth[0]);
    load_t(1);                            // nt >= 2 always
    LGKM_BARRIER();

    if (act) compute(kph[0], vth[0]);     // tile 0
    cvt_write(kph[1], vth[1]);
    if (nt > 2) load_t(2);
    LGKM_BARRIER();

    if (act) compute(kph[1], vth[1]);     // tile 1
    if (nt > 2) {
      cvt_write(kph[0], vth[0]);
      load_t(3);
      LGKM_BARRIER();
      if (act) compute(kph[0], vth[0]);   // tile 2
      cvt_write(kph[1], vth[1]);
      LGKM_BARRIER();
      if (act) compute(kph[1], vth[1]);   // tile 3
    }

    // ---- epilogue: 1/l per q (lane-dim) -> reg-dim via LDS, store fp32 ----
    if (act) {
      if (hi == 0) lsc[w * 32 + qj] = 1.0f / lsum;
      __builtin_amdgcn_wave_barrier();
#pragma unroll
      for (int r = 0; r < 16; ++r) {
        const int row = (r & 3) + 8 * (r >> 2) + 4 * hi;
        const float li = lsc[w * 32 + row];
        float* op = outg + (size_t)(t0 + qbase + row) * RS + h * D + qj;
        op[0]  = acc0[r] * li;
        op[32] = acc1[r] * li;
      }
    }
    // item-top __syncthreads pair orders LDS reuse across items
  }
#undef LGKM_BARRIER
}

extern "C" void kernel_launch(void* const* d_in, const int* in_sizes, int n_in,
                              void* d_out, int out_size, void* d_ws, size_t ws_size,
                              hipStream_t stream) {
  (void)in_sizes; (void)n_in; (void)ws_size; (void)out_size;
  const float* q  = (const float*)d_in[0];
  const float* k  = (const float*)d_in[1];
  const float* v  = (const float*)d_in[2];
  const int*   cu = (const int*)d_in[3];
  float* out = (float*)d_out;
  int*   ctr = (int*)d_ws;

  hipMemsetAsync(ctr, 0, sizeof(int), stream);   // work counter = 0 each launch
  // persistent: 2 blocks/CU x 256 CUs = 512 blocks, work-steal 2048 items
  fa_persist3_kernel<<<dim3(512), dim3(512), 0, stream>>>(q, k, v, cu, out, ctr);
}